// Round 1
// baseline (464.505 us; speedup 1.0000x reference)
//
#include <hip/hip_runtime.h>
#include <stdint.h>

#define N_NODES 20000
#define N_EDGES 100000

typedef __bf16 bf16;
typedef bf16  bf16x8 __attribute__((ext_vector_type(8)));
typedef float f32x4  __attribute__((ext_vector_type(4)));

__device__ __forceinline__ f32x4 mfma16(bf16x8 a, bf16x8 b, f32x4 c) {
  return __builtin_amdgcn_mfma_f32_16x16x32_bf16(a, b, c, 0, 0, 0);
}

__device__ __forceinline__ float silu_(float y) {
  return y / (1.0f + __expf(-y));
}

// ---- workspace layout (bytes) ----
#define OFF_W0T   0u          // [64][32]   mlp_w0/sqrt(8), K zero-padded 8->32
#define OFF_W1T   4096u       // [64][64]   mlp_w1 * SILU_NORM/8
#define OFF_W2T   12288u      // [64][64]   mlp_w2 * SILU_NORM/8
#define OFF_W3T   20480u      // [512][64]  mlp_w3 * SILU_NORM/8
#define OFF_WOS   86016u      // [128][256] W_out_s/16 * (u<128 ? PW_0E : PW_0E*INV_SQRT3)
#define OFF_WOV   151552u     // [128][256] W_out_v/16 * PW_0E   (PW_1O*INV_SQRT3 == PW_0E)
#define OFF_WST   217088u     // [128][128] W_up_s/sqrt(128)
#define OFF_WVT   249856u     // [128][128] W_up_v/sqrt(128)
#define OFF_SUP   282624u     // [20000][128] bf16 s_up
#define OFF_VUP   5402624u    // [20000][384] bf16 v_up, layout [n][i][u]

// ---------------- K0: weight prep (transpose + scale + bf16) ----------------
__global__ __launch_bounds__(256) void k0_prep(
    const float* __restrict__ wus, const float* __restrict__ wuv,
    const float* __restrict__ w0,  const float* __restrict__ w1,
    const float* __restrict__ w2,  const float* __restrict__ w3,
    const float* __restrict__ wos_g, const float* __restrict__ wov_g,
    char* __restrict__ ws) {
  const int idx = blockIdx.x * 256 + threadIdx.x;  // 0..32767
  bf16* W0T = (bf16*)(ws + OFF_W0T);
  bf16* W1T = (bf16*)(ws + OFF_W1T);
  bf16* W2T = (bf16*)(ws + OFF_W2T);
  bf16* W3T = (bf16*)(ws + OFF_W3T);
  bf16* WOS = (bf16*)(ws + OFF_WOS);
  bf16* WOV = (bf16*)(ws + OFF_WOV);
  bf16* WST = (bf16*)(ws + OFF_WST);
  bf16* WVT = (bf16*)(ws + OFF_WVT);

  const float cS   = 0.08838834764831845f;   // 1/sqrt(128)
  const float c0   = 0.35355339059327373f;   // 1/sqrt(8)
  const float c12  = 1.6790390826f / 8.0f;   // SILU_NORM/sqrt(64)
  const float cosA = 0.04419417382415922f;   // PW_0E/16
  const float cosB = 0.025515518153991442f;  // PW_0E*INV_SQRT3/16
  const float cov  = 0.04419417382415922f;   // PW_1O*INV_SQRT3/16 == PW_0E/16

  if (idx < 16384) {
    int w = idx >> 7, u = idx & 127;
    WST[idx] = (bf16)(wus[u * 128 + w] * cS);
    WVT[idx] = (bf16)(wuv[u * 128 + w] * cS);
  }
  if (idx < 2048) {
    int h = idx >> 5, r = idx & 31;
    W0T[idx] = (bf16)((r < 8) ? w0[r * 64 + h] * c0 : 0.0f);
  }
  if (idx < 4096) {
    int h = idx >> 6, k = idx & 63;
    W1T[idx] = (bf16)(w1[k * 64 + h] * c12);
    W2T[idx] = (bf16)(w2[k * 64 + h] * c12);
  }
  {
    int j = idx >> 6, k = idx & 63;
    W3T[idx] = (bf16)(w3[k * 512 + j] * c12);
    int w = idx >> 8, u = idx & 255;
    WOS[idx] = (bf16)(wos_g[u * 128 + w] * ((u < 128) ? cosA : cosB));
    WOV[idx] = (bf16)(wov_g[u * 128 + w] * cov);
  }
}

// ---------------- K1: node up-projection ----------------
__global__ __launch_bounds__(256, 4) void k1_nodeup(const float* __restrict__ nf,
                                                    char* __restrict__ ws) {
  __shared__ __align__(16) bf16 tiles[4][32 * 136];  // [stream][row][K pad 136]
  const int n0 = blockIdx.x * 32;
  const int t = threadIdx.x;

  #pragma unroll
  for (int p = 0; p < 16; p++) {
    int idx = p * 256 + t;           // 0..4095
    int r = idx >> 7, c4 = idx & 127;
    const float4 f = *(const float4*)&nf[(size_t)(n0 + r) * 512 + c4 * 4];
    float vals[4] = {f.x, f.y, f.z, f.w};
    #pragma unroll
    for (int e2 = 0; e2 < 4; e2++) {
      int g = c4 * 4 + e2;
      if (g < 128) {
        tiles[0][r * 136 + g] = (bf16)vals[e2];
      } else {
        int gg = g - 128;
        int u = gg / 3, i = gg - 3 * u;
        tiles[1 + i][r * 136 + u] = (bf16)vals[e2];
      }
    }
  }
  __syncthreads();

  const int wv = t >> 6, lane = t & 63;
  const int m = lane & 15, q = lane >> 4;
  const bf16* BT = (const bf16*)(ws + ((wv == 0) ? OFF_WST : OFF_WVT));
  const bf16* At = tiles[wv];

  const f32x4 z = {0.f, 0.f, 0.f, 0.f};
  f32x4 acc[2][8] = {{z, z, z, z, z, z, z, z}, {z, z, z, z, z, z, z, z}};
  #pragma unroll
  for (int kk = 0; kk < 128; kk += 32) {
    bf16x8 af0 = *(const bf16x8*)&At[m * 136 + kk + q * 8];
    bf16x8 af1 = *(const bf16x8*)&At[(16 + m) * 136 + kk + q * 8];
    #pragma unroll
    for (int nt = 0; nt < 8; nt++) {
      bf16x8 bfr = *(const bf16x8*)&BT[(nt * 16 + m) * 128 + kk + q * 8];
      acc[0][nt] = mfma16(af0, bfr, acc[0][nt]);
      acc[1][nt] = mfma16(af1, bfr, acc[1][nt]);
    }
  }

  bf16* sup = (bf16*)(ws + OFF_SUP);
  bf16* vup = (bf16*)(ws + OFF_VUP);
  #pragma unroll
  for (int rt = 0; rt < 2; rt++) {
    #pragma unroll
    for (int nt = 0; nt < 8; nt++) {
      int col = nt * 16 + m;
      #pragma unroll
      for (int r = 0; r < 4; r++) {
        int node = n0 + rt * 16 + q * 4 + r;
        if (wv == 0) sup[node * 128 + col] = (bf16)acc[rt][nt][r];
        else         vup[node * 384 + (wv - 1) * 128 + col] = (bf16)acc[rt][nt][r];
      }
    }
  }
}

// ---------------- K23: fused edge MLP + tensor product + out-projection ----
// Restructure vs previous version:
//  * sup/vup gathers issued ONCE at kernel start via global_load_lds (direct
//    HBM->LDS, per-lane gather source, linear LDS dest); latency overlaps the
//    whole edge-MLP instead of being exposed in 4 barrier-bounded phases.
//  * gathered rows XOR-swizzled (inverse swizzle on GLOBAL src, swizzle on
//    LDS read) to break the 256B/768B row-stride bank conflicts.
//  * A-matrix staging buffer eliminated: each wave builds its MFMA
//    A-fragments on the fly from tpw/supL/vupL (identical math).
//  * tpw computed in two 256-col halves (h0 fragments kept in registers) so
//    everything fits in 49,664 B LDS -> 3 blocks/CU; barriers 14 -> 7.
#define L_TPW   0
#define L_H0    0              /* alias: 32x72 bf16 = 4608, dead before tpw */
#define L_H1    4608           /* alias: 32x72 bf16 = 4608, dead before tpw */
#define L_SUP   16896          /* 32 x 128 bf16 = 8192  (swizzled chunks)   */
#define L_VUP   25088          /* 32 x 384 bf16 = 24576 (swizzled chunks)   */
#define L_TOT   49664
#define TPW_LD  264            /* 256 + 8 pad */

#define GLOAD_LDS16(gsrc, ldst) __builtin_amdgcn_global_load_lds( \
    (const __attribute__((address_space(1))) void*)(gsrc),        \
    (__attribute__((address_space(3))) void*)(ldst), 16, 0, 0)

// read logical 16B chunk (elem multiple of 8) of a gathered row with swizzle
__device__ __forceinline__ bf16x8 ldsw8(const bf16* row, int elem, int sw) {
  int c = elem >> 3;
  int cs = (c & ~7) | ((c ^ sw) & 7);
  return *(const bf16x8*)&row[cs * 8];
}

__device__ __forceinline__ bf16x8 build_frag(
    int wv, int ii, int kc, int off /* kk + q*8 */,
    const bf16* tpr, const bf16* supR, const bf16* vupR, int sw,
    float4 at, float s1i) {
  bf16x8 af;
  if (kc < 2) {
    const int K = kc * 64 + off;                   // 0..127
    bf16x8 sv = ldsw8(supR, K, sw);
    if (wv == 0) {                                 // a0 = w00*ss*sh0
      bf16x8 tv = *(const bf16x8*)&tpr[K];
      #pragma unroll
      for (int j = 0; j < 8; j++)
        af[j] = (bf16)((float)tv[j] * (float)sv[j] * at.x);
    } else {                                       // a1 = w01*ss*sh1_i
      bf16x8 tv = *(const bf16x8*)&tpr[128 + K];
      #pragma unroll
      for (int j = 0; j < 8; j++)
        af[j] = (bf16)((float)tv[j] * (float)sv[j] * s1i);
    }
  } else {
    const int Kl = (kc - 2) * 64 + off;            // 0..127
    if (wv == 0) {                                 // b0 = w11*(vs.sh1)
      bf16x8 tv = *(const bf16x8*)&tpr[128 + Kl];  // global col 384+Kl
      bf16x8 vx = ldsw8(vupR, Kl, sw);
      bf16x8 vy = ldsw8(vupR, 128 + Kl, sw);
      bf16x8 vz = ldsw8(vupR, 256 + Kl, sw);
      #pragma unroll
      for (int j = 0; j < 8; j++) {
        float dv = (float)vx[j] * at.y + (float)vy[j] * at.z + (float)vz[j] * at.w;
        af[j] = (bf16)((float)tv[j] * dv);
      }
    } else {                                       // b1 = w10*sh0*vs_i
      bf16x8 tv = *(const bf16x8*)&tpr[Kl];        // global col 256+Kl
      bf16x8 vv = ldsw8(vupR, ii * 128 + Kl, sw);
      #pragma unroll
      for (int j = 0; j < 8; j++)
        af[j] = (bf16)((float)tv[j] * at.x * (float)vv[j]);
    }
  }
  return af;
}

__global__ __launch_bounds__(256, 3) void k23_fused(
    const float* __restrict__ efeat, const float* __restrict__ attrs,
    const int* __restrict__ sender, const char* __restrict__ ws,
    float* __restrict__ out) {
  __shared__ __align__(16) char smem[L_TOT];
  bf16* tpwH = (bf16*)(smem + L_TPW);
  bf16* h0   = (bf16*)(smem + L_H0);
  bf16* h1   = (bf16*)(smem + L_H1);
  bf16* supL = (bf16*)(smem + L_SUP);
  bf16* vupL = (bf16*)(smem + L_VUP);

  const int e0 = blockIdx.x * 32;
  const int t = threadIdx.x;
  const int wv = t >> 6, lane = t & 63;
  const int m = lane & 15, q = lane >> 4;
  const f32x4 z = {0.f, 0.f, 0.f, 0.f};

  // ---- issue the full edge gather immediately: 8+24 global_load_lds ----
  {
    #pragma unroll
    for (int jj = 0; jj < 2; jj++) {               // sup: 512 x 16B chunks
      int j = wv * 2 + jj;
      int f = j * 64 + lane;                       // 0..511
      int e = f >> 4, c = f & 15;
      int se = sender[e0 + e];
      int cs = c ^ (e & 7);                        // inverse swizzle on src
      GLOAD_LDS16(ws + OFF_SUP + (size_t)se * 256 + cs * 16,
                  (char*)supL + j * 1024);
    }
    #pragma unroll
    for (int jj = 0; jj < 6; jj++) {               // vup: 1536 x 16B chunks
      int j = wv * 6 + jj;
      int f = j * 64 + lane;                       // 0..1535
      int e = f / 48, c = f - e * 48;
      int se = sender[e0 + e];
      int cs = (c & ~7) | ((c ^ e) & 7);
      GLOAD_LDS16(ws + OFF_VUP + (size_t)se * 768 + cs * 16,
                  (char*)vupL + j * 1024);
    }
  }

  const bf16* W0T = (const bf16*)(ws + OFF_W0T);
  const bf16* W1T = (const bf16*)(ws + OFF_W1T);
  const bf16* W2T = (const bf16*)(ws + OFF_W2T);
  const bf16* W3T = (const bf16*)(ws + OFF_W3T);

  const int rt = wv & 1, nh = wv >> 1;

  { // layer 0: efeat (32x8, zero-padded to K=32) @ W0T -> h0. A built in-reg.
    bf16x8 af;
    #pragma unroll
    for (int j = 0; j < 8; j++) af[j] = (bf16)0.0f;
    if (q == 0) {
      const float4* ef4 = (const float4*)efeat;
      float4 u0 = ef4[(size_t)(e0 + rt * 16 + m) * 2 + 0];
      float4 u1 = ef4[(size_t)(e0 + rt * 16 + m) * 2 + 1];
      af[0] = (bf16)u0.x; af[1] = (bf16)u0.y; af[2] = (bf16)u0.z; af[3] = (bf16)u0.w;
      af[4] = (bf16)u1.x; af[5] = (bf16)u1.y; af[6] = (bf16)u1.z; af[7] = (bf16)u1.w;
    }
    f32x4 acc[2] = {z, z};
    #pragma unroll
    for (int ntl = 0; ntl < 2; ntl++) {
      bf16x8 bfr = *(const bf16x8*)&W0T[((nh * 2 + ntl) * 16 + m) * 32 + q * 8];
      acc[ntl] = mfma16(af, bfr, acc[ntl]);
    }
    #pragma unroll
    for (int ntl = 0; ntl < 2; ntl++)
      #pragma unroll
      for (int r = 0; r < 4; r++)
        h0[(rt * 16 + q * 4 + r) * 72 + (nh * 2 + ntl) * 16 + m] = (bf16)silu_(acc[ntl][r]);
  }
  __syncthreads();  // B1 (also drains the gather DMA, overlapped with L0)

  { // layer 1: h0 @ W1T -> h1
    f32x4 acc[2] = {z, z};
    #pragma unroll
    for (int kk = 0; kk < 64; kk += 32) {
      bf16x8 af = *(const bf16x8*)&h0[(rt * 16 + m) * 72 + kk + q * 8];
      #pragma unroll
      for (int ntl = 0; ntl < 2; ntl++) {
        bf16x8 bfr = *(const bf16x8*)&W1T[((nh * 2 + ntl) * 16 + m) * 64 + kk + q * 8];
        acc[ntl] = mfma16(af, bfr, acc[ntl]);
      }
    }
    #pragma unroll
    for (int ntl = 0; ntl < 2; ntl++)
      #pragma unroll
      for (int r = 0; r < 4; r++)
        h1[(rt * 16 + q * 4 + r) * 72 + (nh * 2 + ntl) * 16 + m] = (bf16)silu_(acc[ntl][r]);
  }
  __syncthreads();  // B2

  { // layer 2: h1 @ W2T -> h0
    f32x4 acc[2] = {z, z};
    #pragma unroll
    for (int kk = 0; kk < 64; kk += 32) {
      bf16x8 af = *(const bf16x8*)&h1[(rt * 16 + m) * 72 + kk + q * 8];
      #pragma unroll
      for (int ntl = 0; ntl < 2; ntl++) {
        bf16x8 bfr = *(const bf16x8*)&W2T[((nh * 2 + ntl) * 16 + m) * 64 + kk + q * 8];
        acc[ntl] = mfma16(af, bfr, acc[ntl]);
      }
    }
    __syncthreads();  // B3: all h1 reads done AND h0 reads (layer1) long done
    #pragma unroll
    for (int ntl = 0; ntl < 2; ntl++)
      #pragma unroll
      for (int r = 0; r < 4; r++)
        h0[(rt * 16 + q * 4 + r) * 72 + (nh * 2 + ntl) * 16 + m] = (bf16)silu_(acc[ntl][r]);
  }
  __syncthreads();  // B3b: h0 final ready

  // keep layer-3 A-fragments (h0) in registers; h0/h1 LDS dies after this
  bf16x8 hf0 = *(const bf16x8*)&h0[(rt * 16 + m) * 72 + 0  + q * 8];
  bf16x8 hf1 = *(const bf16x8*)&h0[(rt * 16 + m) * 72 + 32 + q * 8];
  __syncthreads();  // B4: hf loads complete before tpw overwrites this region

  // ---- per-lane tensor-product context ----
  const int eA = m, eB = 16 + m;                   // af0 edge, af1 edge
  const int sw = m & 7;                            // (16+m)&7 == m&7
  const float4* at4 = (const float4*)attrs;
  const float4 atA = at4[e0 + eA];
  const float4 atB = at4[e0 + eB];
  const int ii = wv - 1;                           // valid for wv>0
  const float s1A = (ii == 0) ? atA.y : ((ii == 1) ? atA.z : atA.w);
  const float s1B = (ii == 0) ? atB.y : ((ii == 1) ? atB.z : atB.w);
  const bf16* tprA = tpwH + eA * TPW_LD;
  const bf16* tprB = tpwH + eB * TPW_LD;
  const bf16* supA = supL + eA * 128;
  const bf16* supB = supL + eB * 128;
  const bf16* vupA = vupL + eA * 384;
  const bf16* vupB = vupL + eB * 384;
  const bf16* WB = (const bf16*)(ws + ((wv == 0) ? OFF_WOS : OFF_WOV));

  f32x4 acc0[8] = {z, z, z, z, z, z, z, z};
  f32x4 acc1[8] = {z, z, z, z, z, z, z, z};

  #pragma unroll
  for (int half = 0; half < 2; half++) {
    if (half) __syncthreads();  // B6: kc0/kc1 tpw reads done before overwrite

    { // layer 3 (half): h0-frags (regs) @ W3T[half*256 .. +256) -> tpwH
      #pragma unroll 2
      for (int i = 0; i < 8; i++) {
        int ntg = (wv >> 1) * 8 + i;               // 0..15 per half
        f32x4 acc = z;
        const bf16* wb = &W3T[(size_t)((half * 16 + ntg) * 16 + m) * 64 + q * 8];
        bf16x8 b0 = *(const bf16x8*)&wb[0];
        bf16x8 b1 = *(const bf16x8*)&wb[32];
        acc = mfma16(hf0, b0, acc);
        acc = mfma16(hf1, b1, acc);
        #pragma unroll
        for (int r = 0; r < 4; r++)
          tpwH[(rt * 16 + q * 4 + r) * TPW_LD + ntg * 16 + m] = (bf16)acc[r];
      }
    }
    __syncthreads();  // B5/B7: tpw half ready (first pass: gathers long drained)

    // ---- two barrier-free TP+out-projection K-phases ----
    #pragma unroll
    for (int kci = 0; kci < 2; kci++) {
      const int kc = half * 2 + kci;
      const int kb = kc * 64;
      #pragma unroll
      for (int kk = 0; kk < 64; kk += 32) {
        bf16x8 af0 = build_frag(wv, ii, kc, kk + q * 8, tprA, supA, vupA, sw, atA, s1A);
        bf16x8 af1 = build_frag(wv, ii, kc, kk + q * 8, tprB, supB, vupB, sw, atB, s1B);
        #pragma unroll
        for (int nt = 0; nt < 8; nt++) {
          bf16x8 bfr = *(const bf16x8*)&WB[(nt * 16 + m) * 256 + kb + kk + q * 8];
          acc0[nt] = mfma16(af0, bfr, acc0[nt]);
          acc1[nt] = mfma16(af1, bfr, acc1[nt]);
        }
      }
    }
  }

  // epilogue (unchanged)
  #pragma unroll
  for (int b = 0; b < 2; b++) {
    const f32x4* accp = b ? acc1 : acc0;
    int rb = wv * 32 + b * 16 + q * 4;
    #pragma unroll
    for (int nt = 0; nt < 8; nt++) {
      int col = nt * 16 + m;
      #pragma unroll
      for (int r = 0; r < 4; r++) {
        int row = rb + r;
        float v = accp[nt][r];
        if (wv == 0) {
          out[(size_t)(e0 + row) * 512 + col] = v;                // out_s
        } else {
          int i2 = (row - 32) >> 5, eL2 = (row - 32) & 31;
          out[(size_t)(e0 + eL2) * 512 + 128 + 3 * col + i2] = v; // out_v[w][i]
        }
      }
    }
  }
}

extern "C" void kernel_launch(void* const* d_in, const int* in_sizes, int n_in,
                              void* d_out, int out_size, void* d_ws, size_t ws_size,
                              hipStream_t stream) {
  const float* node_feats = (const float*)d_in[0];
  const float* edge_attrs = (const float*)d_in[1];
  const float* edge_feats = (const float*)d_in[2];
  const int*   edge_index = (const int*)d_in[3];
  const float* W_up_s = (const float*)d_in[4];
  const float* W_up_v = (const float*)d_in[5];
  const float* w0 = (const float*)d_in[6];
  const float* w1 = (const float*)d_in[7];
  const float* w2 = (const float*)d_in[8];
  const float* w3 = (const float*)d_in[9];
  const float* Wos = (const float*)d_in[10];
  const float* Wov = (const float*)d_in[11];
  float* out = (float*)d_out;
  char* ws = (char*)d_ws;

  k0_prep<<<dim3(128), dim3(256), 0, stream>>>(W_up_s, W_up_v, w0, w1, w2, w3,
                                               Wos, Wov, ws);
  k1_nodeup<<<dim3(625), dim3(256), 0, stream>>>(node_feats, ws);
  k23_fused<<<dim3(3125), dim3(256), 0, stream>>>(edge_feats, edge_attrs,
                                                  edge_index, ws, out);
}